// Round 14
// baseline (388.431 us; speedup 1.0000x reference)
//
#include <hip/hip_runtime.h>
#include <hip/hip_bf16.h>
#include <stdint.h>

typedef __bf16 bf16_t;
typedef bf16_t bf16x8 __attribute__((ext_vector_type(8)));
typedef float f32x4 __attribute__((ext_vector_type(4)));

#define IN_F 4096
#define OUT_F 4096
#define M_ROWS 8192
#define RANK 16

// ---------------------------------------------------------------------------
// Kernel 1: dequantize 4-bit -> fp32, fold LoRA (Wp = W + B*A), store bf16.
// (r8/r13 version verbatim.)
// ---------------------------------------------------------------------------
__global__ __launch_bounds__(256)
void dequant_lora_kernel(const int* __restrict__ qw, const float* __restrict__ wmax,
                         const float* __restrict__ lA, const float* __restrict__ lB,
                         bf16_t* __restrict__ Wp) {
  const int bid = blockIdx.x;
  const int bo = bid >> 4;
  const int bi = bid & 15;
  const int t  = threadIdx.x;
  const int o  = bo * 8 + (t >> 5);
  const int i0 = bi * 256 + (t & 31) * 8;
  const int f0 = o * IN_F + i0;

  const int4 q4 = *(const int4*)(qw + (f0 >> 1));
  const float scale = wmax[f0 >> 6];
  const float st = scale * (2.0f / 15.0f);

  float v[8];
  {
    const int q0 = q4.x, q1 = q4.y, q2 = q4.z, q3 = q4.w;
    v[0] = (float)(q0 & 15)        * st - scale;
    v[1] = (float)((q0 >> 4) & 15) * st - scale;
    v[2] = (float)(q1 & 15)        * st - scale;
    v[3] = (float)((q1 >> 4) & 15) * st - scale;
    v[4] = (float)(q2 & 15)        * st - scale;
    v[5] = (float)((q2 >> 4) & 15) * st - scale;
    v[6] = (float)(q3 & 15)        * st - scale;
    v[7] = (float)((q3 >> 4) & 15) * st - scale;
  }

  const float* Brow = lB + o * RANK;
#pragma unroll
  for (int r = 0; r < RANK; ++r) {
    const float br = Brow[r];
    const float4 a0 = *(const float4*)(lA + r * IN_F + i0);
    const float4 a1 = *(const float4*)(lA + r * IN_F + i0 + 4);
    v[0] += br * a0.x; v[1] += br * a0.y; v[2] += br * a0.z; v[3] += br * a0.w;
    v[4] += br * a1.x; v[5] += br * a1.y; v[6] += br * a1.z; v[7] += br * a1.w;
  }

  bf16x8 ov;
#pragma unroll
  for (int j = 0; j < 8; ++j) ov[j] = (bf16_t)v[j];
  *(bf16x8*)(Wp + (size_t)f0) = ov;
}

// ---------------------------------------------------------------------------
// Kernel 2: x fp32 -> bf16 (vectorized, separate launch)
// ---------------------------------------------------------------------------
__global__ __launch_bounds__(256)
void f32_to_bf16_kernel(const float* __restrict__ x, bf16_t* __restrict__ xb) {
  const size_t tid = (size_t)blockIdx.x * 256 + threadIdx.x;
  const float4 a0 = *(const float4*)(x + tid * 8);
  const float4 a1 = *(const float4*)(x + tid * 8 + 4);
  bf16x8 o;
  o[0] = (bf16_t)a0.x; o[1] = (bf16_t)a0.y; o[2] = (bf16_t)a0.z; o[3] = (bf16_t)a0.w;
  o[4] = (bf16_t)a1.x; o[5] = (bf16_t)a1.y; o[6] = (bf16_t)a1.z; o[7] = (bf16_t)a1.w;
  *(bf16x8*)(xb + tid * 8) = o;
}

// ---------------------------------------------------------------------------
// Kernel 3: 256x256 GEMM, 4 waves x 128x128 wave-tile (perimeter cut:
// LDS frag reads 192 KB -> 128 KB per block-tile; MFMA volume unchanged).
// acc[8][8] f32x4 = 256 regs; ~360 total (<450 spill line). 16x16x32 MFMA,
// proven conflict-free swizzle family, r2-phase schedule, counted vmcnt(16).
// Staging: 16 gloads/tile (256 thr): A(t+1) halves at ph0/ph1 -> buf cur^1;
// B(t+2) halves at ph2/ph3 -> buf cur (B(cur) fully consumed in ph0).
// ---------------------------------------------------------------------------
__device__ __forceinline__ void gld(const bf16_t* src, char* dst) {
  __builtin_amdgcn_global_load_lds((const __attribute__((address_space(1))) void*)src,
                                   (__attribute__((address_space(3))) void*)dst, 16, 0, 0);
}

#define BARRIER() __builtin_amdgcn_s_barrier()
#define WAIT_LGKM0() do { asm volatile("s_waitcnt lgkmcnt(0)" ::: "memory"); \
                          __builtin_amdgcn_sched_barrier(0); } while (0)
#define WAIT_VM(n) asm volatile("s_waitcnt vmcnt(" #n ")" ::: "memory")

#define LDA(buf, m, cb) (*(const bf16x8*)(ldsA + ((buf)*32768 + aRowB + (m)*2048 + (cb))))
#define LDB(buf, n, cb) (*(const bf16x8*)(ldsB + ((buf)*32768 + bRowB + (n)*2048 + (cb))))

// half-stage: 8 gloads, 32-row groups g = 4h .. 4h+3  (group = 4096 B)
#define STAGE_A_H(kt, buf, h) do { \
  _Pragma("unroll") for (int g2 = 0; g2 < 4; ++g2) \
    gld(Asrc + ((size_t)((h)*4+g2)*32*IN_F + (size_t)(kt)*64), \
        ldsA + ((buf)*32768 + ((h)*4+g2)*4096 + tid*16)); \
} while (0)
#define STAGE_B_H(kt, buf, h) do { \
  _Pragma("unroll") for (int g2 = 0; g2 < 4; ++g2) \
    gld(Bsrc + ((size_t)((h)*4+g2)*32*IN_F + (size_t)(kt)*64), \
        ldsB + ((buf)*32768 + ((h)*4+g2)*4096 + tid*16)); \
} while (0)

#define READ_B_ALL(buf) do { \
  _Pragma("unroll") for (int n = 0; n < 8; ++n) { \
    bT[n][0] = LDB(buf, n, cA0); bT[n][1] = LDB(buf, n, cA1); } \
} while (0)

#define PHASE(Q, EXTRA, STG, TW) do { \
  aF[0][0] = LDA(cur, 2*(Q),   cA0); aF[0][1] = LDA(cur, 2*(Q),   cA1); \
  aF[1][0] = LDA(cur, 2*(Q)+1, cA0); aF[1][1] = LDA(cur, 2*(Q)+1, cA1); \
  EXTRA; STG; \
  BARRIER(); \
  WAIT_LGKM0(); \
  __builtin_amdgcn_s_setprio(1); \
  _Pragma("unroll") for (int kh = 0; kh < 2; ++kh) \
    _Pragma("unroll") for (int mm = 0; mm < 2; ++mm) \
      _Pragma("unroll") for (int n = 0; n < 8; ++n) \
        acc[2*(Q)+mm][n] = __builtin_amdgcn_mfma_f32_16x16x32_bf16( \
            aF[mm][kh], bT[n][kh], acc[2*(Q)+mm][n], 0, 0, 0); \
  __builtin_amdgcn_s_setprio(0); \
  TW; \
  BARRIER(); \
} while (0)

__global__ __launch_bounds__(256)
void gemm_w128_kernel(const bf16_t* __restrict__ Xb, const bf16_t* __restrict__ Wp,
                      const float* __restrict__ bias, float* __restrict__ C) {
  __shared__ __align__(16) bf16_t As[2 * 16384];   // 64 KiB [2buf][256 rows][64]
  __shared__ __align__(16) bf16_t Bs[2 * 16384];   // 64 KiB
  char* ldsA = (char*)As;
  char* ldsB = (char*)Bs;

  const int tid  = threadIdx.x;
  const int lane = tid & 63;
  const int wave = tid >> 6;          // 0..3
  const int wr = wave >> 1;           // 0..1 -> M half (128 rows)
  const int wc = wave & 1;            // 0..1 -> N half (128 cols)
  const int r16 = lane & 15;
  const int kg  = lane >> 4;          // 0..3

  const int bid = blockIdx.x;
  const int bm = bid >> 4;            // 0..31
  const int bn = bid & 15;            // 0..15

  // staging: linear dest; source col inverse-XOR'd (proven pair)
  const int sr = tid >> 3;                          // 0..31 (+g*32)
  const int sc = ((tid & 7) ^ (sr & 7)) << 3;       // element col (swizzled)
  const bf16_t* Asrc = Xb + (size_t)(bm * 256 + sr) * IN_F + sc;
  const bf16_t* Bsrc = Wp + (size_t)(bn * 256 + sr) * IN_F + sc;

  // read-side offsets (proven conflict-free family)
  const int aRowB = (wr * 128 + r16) * 128;         // + m*2048, m 0..7
  const int bRowB = (wc * 128 + r16) * 128;         // + n*2048, n 0..7
  const int cA0 = (kg * 16) ^ ((r16 & 7) << 4);
  const int cA1 = cA0 ^ 64;

  f32x4 acc[8][8] = {};                             // 256 VGPR
  bf16x8 aF[2][2], bT[8][2];

  // prologue (mirrors steady state): A0,B0 then B1; drain to newest 16
  STAGE_A_H(0, 0, 0); STAGE_A_H(0, 0, 1);
  STAGE_B_H(0, 0, 0); STAGE_B_H(0, 0, 1);
  STAGE_B_H(1, 1, 0); STAGE_B_H(1, 1, 1);
  WAIT_VM(16);               // A0,B0 landed; B1's 16 in flight
  BARRIER();

  for (int t = 0; t < 64; ++t) {
    const int cur = t & 1;
    PHASE(0, READ_B_ALL(cur),
          { if (t < 63) STAGE_A_H(t + 1, cur ^ 1, 0); }, {});
    PHASE(1, {},
          { if (t < 63) STAGE_A_H(t + 1, cur ^ 1, 1); }, {});
    PHASE(2, {},
          { if (t < 62) STAGE_B_H(t + 2, cur, 0); }, {});
    PHASE(3, {},
          { if (t < 62) STAGE_B_H(t + 2, cur, 1); },
          { if (t < 62) { WAIT_VM(16); } else if (t == 62) { WAIT_VM(0); } });
  }

  // epilogue: C/D layout col=lane&15, row=kg*4+reg (m89-verified)
#pragma unroll
  for (int n = 0; n < 8; ++n) {
    const int col = bn * 256 + wc * 128 + n * 16 + r16;
    const float bv = bias[col];
#pragma unroll
    for (int m = 0; m < 8; ++m) {
      const int row0 = bm * 256 + wr * 128 + m * 16 + kg * 4;
#pragma unroll
      for (int r = 0; r < 4; ++r)
        C[(size_t)(row0 + r) * OUT_F + col] = acc[m][n][r] + bv;
    }
  }
}

// ---------------------------------------------------------------------------
extern "C" void kernel_launch(void* const* d_in, const int* in_sizes, int n_in,
                              void* d_out, int out_size, void* d_ws, size_t ws_size,
                              hipStream_t stream) {
  const float* x  = (const float*)d_in[0];
  const int*   qw = (const int*)d_in[1];
  const float* wm = (const float*)d_in[2];
  const float* lA = (const float*)d_in[3];
  const float* lB = (const float*)d_in[4];
  const float* bs = (const float*)d_in[5];
  float* out = (float*)d_out;

  bf16_t* Wp = (bf16_t*)d_ws;                                        // 33.5 MB
  bf16_t* Xb = (bf16_t*)((char*)d_ws + (size_t)OUT_F * IN_F * 2);    // 67 MB

  dequant_lora_kernel<<<8192, 256, 0, stream>>>(qw, wm, lA, lB, Wp);
  f32_to_bf16_kernel<<<M_ROWS * IN_F / 8 / 256, 256, 0, stream>>>(x, Xb);
  gemm_w128_kernel<<<(M_ROWS / 256) * (OUT_F / 256), 256, 0, stream>>>(Xb, Wp, bs, out);
}

// Round 15
// 315.185 us; speedup vs baseline: 1.2324x; 1.2324x over previous
//
#include <hip/hip_runtime.h>
#include <hip/hip_bf16.h>
#include <stdint.h>

typedef __bf16 bf16_t;
typedef bf16_t bf16x8 __attribute__((ext_vector_type(8)));
typedef float f32x4 __attribute__((ext_vector_type(4)));

#define IN_F 4096
#define OUT_F 4096
#define M_ROWS 8192
#define RANK 16

// ---------------------------------------------------------------------------
// Kernel 1: dequantize 4-bit -> fp32, fold LoRA (Wp = W + B*A), store bf16.
// Block covers 8 o-rows x 256 i-cols so lora_A is fetched once per block.
// ---------------------------------------------------------------------------
__global__ __launch_bounds__(256)
void dequant_lora_kernel(const int* __restrict__ qw, const float* __restrict__ wmax,
                         const float* __restrict__ lA, const float* __restrict__ lB,
                         bf16_t* __restrict__ Wp) {
  const int bid = blockIdx.x;
  const int bo = bid >> 4;
  const int bi = bid & 15;
  const int t  = threadIdx.x;
  const int o  = bo * 8 + (t >> 5);
  const int i0 = bi * 256 + (t & 31) * 8;
  const int f0 = o * IN_F + i0;

  const int4 q4 = *(const int4*)(qw + (f0 >> 1));
  const float scale = wmax[f0 >> 6];
  const float st = scale * (2.0f / 15.0f);

  float v[8];
  {
    const int q0 = q4.x, q1 = q4.y, q2 = q4.z, q3 = q4.w;
    v[0] = (float)(q0 & 15)        * st - scale;
    v[1] = (float)((q0 >> 4) & 15) * st - scale;
    v[2] = (float)(q1 & 15)        * st - scale;
    v[3] = (float)((q1 >> 4) & 15) * st - scale;
    v[4] = (float)(q2 & 15)        * st - scale;
    v[5] = (float)((q2 >> 4) & 15) * st - scale;
    v[6] = (float)(q3 & 15)        * st - scale;
    v[7] = (float)((q3 >> 4) & 15) * st - scale;
  }

  const float* Brow = lB + o * RANK;
#pragma unroll
  for (int r = 0; r < RANK; ++r) {
    const float br = Brow[r];
    const float4 a0 = *(const float4*)(lA + r * IN_F + i0);
    const float4 a1 = *(const float4*)(lA + r * IN_F + i0 + 4);
    v[0] += br * a0.x; v[1] += br * a0.y; v[2] += br * a0.z; v[3] += br * a0.w;
    v[4] += br * a1.x; v[5] += br * a1.y; v[6] += br * a1.z; v[7] += br * a1.w;
  }

  bf16x8 ov;
#pragma unroll
  for (int j = 0; j < 8; ++j) ov[j] = (bf16_t)v[j];
  *(bf16x8*)(Wp + (size_t)f0) = ov;
}

// ---------------------------------------------------------------------------
// Kernel 2: x fp32 -> bf16 (vectorized, separate launch)
// ---------------------------------------------------------------------------
__global__ __launch_bounds__(256)
void f32_to_bf16_kernel(const float* __restrict__ x, bf16_t* __restrict__ xb) {
  const size_t tid = (size_t)blockIdx.x * 256 + threadIdx.x;
  const float4 a0 = *(const float4*)(x + tid * 8);
  const float4 a1 = *(const float4*)(x + tid * 8 + 4);
  bf16x8 o;
  o[0] = (bf16_t)a0.x; o[1] = (bf16_t)a0.y; o[2] = (bf16_t)a0.z; o[3] = (bf16_t)a0.w;
  o[4] = (bf16_t)a1.x; o[5] = (bf16_t)a1.y; o[6] = (bf16_t)a1.z; o[7] = (bf16_t)a1.w;
  *(bf16x8*)(xb + tid * 8) = o;
}

// ---------------------------------------------------------------------------
// Kernel 3 (r5/r13 verbatim — best measured GEMM: 259-261us, 0 conflicts):
// 256x256 GEMM, 16x16x32 MFMA, 8 waves x 128x64 wave-tile. Register-pipelined
// phases; ONE boundary per tile: barrier -> stage t+2 (8 gloads) -> counted
// WAIT_VM(8) -> barrier -> prefetch next ph0 fragments. Never vmcnt(0) until
// the final drain. B frags double-banked (bFe/bFo).
// ---------------------------------------------------------------------------
__device__ __forceinline__ void gld(const bf16_t* src, char* dst) {
  __builtin_amdgcn_global_load_lds((const __attribute__((address_space(1))) void*)src,
                                   (__attribute__((address_space(3))) void*)dst, 16, 0, 0);
}

#define BARRIER() __builtin_amdgcn_s_barrier()
#define SBAR()    __builtin_amdgcn_sched_barrier(0)
#define WAIT_VM(n) asm volatile("s_waitcnt vmcnt(" #n ")" ::: "memory")

#define LDA(buf, m, cb) (*(const bf16x8*)(ldsA + ((buf)*32768 + aRowB + (m)*2048 + (cb))))
#define LDB(buf, n, cb) (*(const bf16x8*)(ldsB + ((buf)*32768 + bRowB + (n)*2048 + (cb))))

#define STAGE_A4(kt, buf) do { \
  _Pragma("unroll") for (int g = 0; g < 4; ++g) \
    gld(Asrc + ((size_t)g*64*IN_F + (size_t)(kt)*64), ldsA + ((buf)*32768 + g*8192 + tid*16)); \
} while (0)
#define STAGE_B4(kt, buf) do { \
  _Pragma("unroll") for (int g = 0; g < 4; ++g) \
    gld(Bsrc + ((size_t)g*64*IN_F + (size_t)(kt)*64), ldsB + ((buf)*32768 + g*8192 + tid*16)); \
} while (0)

#define LOADA2(dst, m0, buf) do { \
  dst[0][0] = LDA(buf, m0,     cA0); dst[0][1] = LDA(buf, m0,     cA1); \
  dst[1][0] = LDA(buf, (m0)+1, cA0); dst[1][1] = LDA(buf, (m0)+1, cA1); \
} while (0)

#define PREFETCH12(buf, BFN) do { \
  LOADA2(aF0, 0, buf); \
  _Pragma("unroll") for (int n = 0; n < 4; ++n) { \
    BFN[n][0] = LDB(buf, n, cA0); BFN[n][1] = LDB(buf, n, cA1); } \
} while (0)

#define MFMA_Q(Q, AF, BF) do { \
  SBAR(); \
  __builtin_amdgcn_s_setprio(1); \
  _Pragma("unroll") for (int kh = 0; kh < 2; ++kh) \
  _Pragma("unroll") for (int mm = 0; mm < 2; ++mm) \
  _Pragma("unroll") for (int n = 0; n < 4; ++n) \
    acc[2*(Q)+mm][n] = __builtin_amdgcn_mfma_f32_16x16x32_bf16( \
        AF[mm][kh], BF[n][kh], acc[2*(Q)+mm][n], 0, 0, 0); \
  __builtin_amdgcn_s_setprio(0); \
} while (0)

#define TILE_BODY(CUR, BFC) do { \
  LOADA2(aF1, 2, CUR); MFMA_Q(0, aF0, BFC); \
  LOADA2(aF0, 4, CUR); MFMA_Q(1, aF1, BFC); \
  LOADA2(aF1, 6, CUR); MFMA_Q(2, aF0, BFC); \
  MFMA_Q(3, aF1, BFC); \
} while (0)

#define TILE_END(CUR, tv, BFN) do { \
  SBAR(); BARRIER(); \
  if ((tv) < 62) { STAGE_A4((tv) + 2, CUR); STAGE_B4((tv) + 2, CUR); \
                   SBAR(); WAIT_VM(8); } \
  else           { WAIT_VM(0); } \
  SBAR(); BARRIER(); SBAR(); \
  PREFETCH12((CUR) ^ 1, BFN); \
} while (0)

__global__ __launch_bounds__(512, 2)
void gemm_pipe_kernel(const bf16_t* __restrict__ Xb, const bf16_t* __restrict__ Wp,
                      const float* __restrict__ bias, float* __restrict__ C) {
  __shared__ __align__(16) bf16_t As[2 * 16384];   // 64 KiB [2buf][256][64]
  __shared__ __align__(16) bf16_t Bs[2 * 16384];   // 64 KiB
  char* ldsA = (char*)As;
  char* ldsB = (char*)Bs;

  const int tid  = threadIdx.x;
  const int lane = tid & 63;
  const int wave = tid >> 6;
  const int wr = wave >> 2;           // 0..1 -> M half
  const int wc = wave & 3;            // 0..3 -> N quarter
  const int r16 = lane & 15;
  const int kg  = lane >> 4;          // 0..3

  const int bid = blockIdx.x;
  const int bm = bid >> 4;            // 0..31
  const int bn = bid & 15;            // 0..15

  // staging: per-thread row + pre-swizzled source column (both-sides pair)
  const int sr = tid >> 3;                          // 0..63
  const int sc = ((tid & 7) ^ (sr & 7)) << 3;       // element col (swizzled)
  const bf16_t* Asrc = Xb + (size_t)(bm * 256 + sr) * IN_F + sc;
  const bf16_t* Bsrc = Wp + (size_t)(bn * 256 + sr) * IN_F + sc;

  // read-side offsets (proven conflict-free addressing family)
  const int aRowB = (wr * 128 + r16) * 128;         // byte row offset in A tile
  const int bRowB = (wc * 64 + r16) * 128;          // byte row offset in B tile
  const int cA0 = (kg * 16) ^ ((r16 & 7) << 4);     // swizzled col byte, k-half 0
  const int cA1 = cA0 ^ 64;                         // k-half 1

  f32x4 acc[8][4] = {};
  bf16x8 aF0[2][2], aF1[2][2], bFe[4][2], bFo[4][2];

  // prologue: stage tiles 0 and 1; prefetch tile-0 ph0 fragments
  STAGE_A4(0, 0); STAGE_B4(0, 0);
  STAGE_A4(1, 1); STAGE_B4(1, 1);
  WAIT_VM(8);                 // tile 0 landed (tile 1's 8 still in flight)
  BARRIER(); SBAR();
  PREFETCH12(0, bFe);

  for (int tt = 0; tt < 62; tt += 2) {
    TILE_BODY(0, bFe); TILE_END(0, tt,     bFo);
    TILE_BODY(1, bFo); TILE_END(1, tt + 1, bFe);
  }
  TILE_BODY(0, bFe); TILE_END(0, 62, bFo);   // t=62 (drains to 0, prefetches t63)
  TILE_BODY(1, bFo);                         // t=63

  // epilogue: C/D layout col=lane&15, row=kg*4+reg (m89-verified)
#pragma unroll
  for (int n = 0; n < 4; ++n) {
    const int col = bn * 256 + wc * 64 + n * 16 + r16;
    const float bv = bias[col];
#pragma unroll
    for (int m = 0; m < 8; ++m) {
      const int row0 = bm * 256 + wr * 128 + m * 16 + kg * 4;
#pragma unroll
      for (int r = 0; r < 4; ++r)
        C[(size_t)(row0 + r) * OUT_F + col] = acc[m][n][r] + bv;
    }
  }
}

// ---------------------------------------------------------------------------
extern "C" void kernel_launch(void* const* d_in, const int* in_sizes, int n_in,
                              void* d_out, int out_size, void* d_ws, size_t ws_size,
                              hipStream_t stream) {
  const float* x  = (const float*)d_in[0];
  const int*   qw = (const int*)d_in[1];
  const float* wm = (const float*)d_in[2];
  const float* lA = (const float*)d_in[3];
  const float* lB = (const float*)d_in[4];
  const float* bs = (const float*)d_in[5];
  float* out = (float*)d_out;

  bf16_t* Wp = (bf16_t*)d_ws;                                        // 33.5 MB
  bf16_t* Xb = (bf16_t*)((char*)d_ws + (size_t)OUT_F * IN_F * 2);    // 67 MB

  dequant_lora_kernel<<<8192, 256, 0, stream>>>(qw, wm, lA, lB, Wp);
  f32_to_bf16_kernel<<<M_ROWS * IN_F / 8 / 256, 256, 0, stream>>>(x, Xb);
  gemm_pipe_kernel<<<(M_ROWS / 256) * (OUT_F / 256), 512, 0, stream>>>(Xb, Wp, bs, out);
}

// Round 16
// 300.073 us; speedup vs baseline: 1.2945x; 1.0504x over previous
//
#include <hip/hip_runtime.h>
#include <hip/hip_bf16.h>
#include <stdint.h>

typedef __bf16 bf16_t;
typedef bf16_t bf16x8 __attribute__((ext_vector_type(8)));
typedef float f32x4 __attribute__((ext_vector_type(4)));

#define IN_F 4096
#define OUT_F 4096
#define M_ROWS 8192
#define RANK 16

// ---------------------------------------------------------------------------
// Kernel 1: dequantize 4-bit -> fp32, fold LoRA (Wp = W + B*A), store bf16.
// Block = 8 o-rows x 256 i-cols. NEW vs r13: the block's lora_A slice
// (16 rank x 256 cols = 16 KB) is staged in LDS once (64 B/thread) instead
// of each thread pulling 512 B from L2 (~1.1 GB aggregate -> ~135 MB).
// LDS fold reads: lanes i/i+32 same address (broadcast), 32 addrs at 32-B
// stride = 2-way banking = free (m136).
// ---------------------------------------------------------------------------
__global__ __launch_bounds__(256)
void dequant_lora_kernel(const int* __restrict__ qw, const float* __restrict__ wmax,
                         const float* __restrict__ lA, const float* __restrict__ lB,
                         bf16_t* __restrict__ Wp) {
  __shared__ float sA[RANK][256];

  const int bid = blockIdx.x;
  const int bo = bid >> 4;
  const int bi = bid & 15;
  const int t  = threadIdx.x;

  // stage lA slice: thread t loads row t>>4, 16 cols starting (t&15)*16
  {
    const int r  = t >> 4;
    const int c0 = (t & 15) * 16;
    const float* src = lA + r * IN_F + bi * 256 + c0;
    *(float4*)&sA[r][c0]      = *(const float4*)(src);
    *(float4*)&sA[r][c0 + 4]  = *(const float4*)(src + 4);
    *(float4*)&sA[r][c0 + 8]  = *(const float4*)(src + 8);
    *(float4*)&sA[r][c0 + 12] = *(const float4*)(src + 12);
  }

  const int o  = bo * 8 + (t >> 5);
  const int il = (t & 31) * 8;            // local i-col within the 256 slice
  const int f0 = o * IN_F + bi * 256 + il;

  const int4 q4 = *(const int4*)(qw + (f0 >> 1));
  const float scale = wmax[f0 >> 6];
  const float st = scale * (2.0f / 15.0f);

  float v[8];
  {
    const int q0 = q4.x, q1 = q4.y, q2 = q4.z, q3 = q4.w;
    v[0] = (float)(q0 & 15)        * st - scale;
    v[1] = (float)((q0 >> 4) & 15) * st - scale;
    v[2] = (float)(q1 & 15)        * st - scale;
    v[3] = (float)((q1 >> 4) & 15) * st - scale;
    v[4] = (float)(q2 & 15)        * st - scale;
    v[5] = (float)((q2 >> 4) & 15) * st - scale;
    v[6] = (float)(q3 & 15)        * st - scale;
    v[7] = (float)((q3 >> 4) & 15) * st - scale;
  }

  __syncthreads();

  const float* Brow = lB + o * RANK;
#pragma unroll
  for (int r = 0; r < RANK; ++r) {
    const float br = Brow[r];
    const float4 a0 = *(const float4*)&sA[r][il];
    const float4 a1 = *(const float4*)&sA[r][il + 4];
    v[0] += br * a0.x; v[1] += br * a0.y; v[2] += br * a0.z; v[3] += br * a0.w;
    v[4] += br * a1.x; v[5] += br * a1.y; v[6] += br * a1.z; v[7] += br * a1.w;
  }

  bf16x8 ov;
#pragma unroll
  for (int j = 0; j < 8; ++j) ov[j] = (bf16_t)v[j];
  *(bf16x8*)(Wp + (size_t)f0) = ov;
}

// ---------------------------------------------------------------------------
// Kernel 2: x fp32 -> bf16 (vectorized, separate launch)
// ---------------------------------------------------------------------------
__global__ __launch_bounds__(256)
void f32_to_bf16_kernel(const float* __restrict__ x, bf16_t* __restrict__ xb) {
  const size_t tid = (size_t)blockIdx.x * 256 + threadIdx.x;
  const float4 a0 = *(const float4*)(x + tid * 8);
  const float4 a1 = *(const float4*)(x + tid * 8 + 4);
  bf16x8 o;
  o[0] = (bf16_t)a0.x; o[1] = (bf16_t)a0.y; o[2] = (bf16_t)a0.z; o[3] = (bf16_t)a0.w;
  o[4] = (bf16_t)a1.x; o[5] = (bf16_t)a1.y; o[6] = (bf16_t)a1.z; o[7] = (bf16_t)a1.w;
  *(bf16x8*)(xb + tid * 8) = o;
}

// ---------------------------------------------------------------------------
// Kernel 3 (r13/r15 verbatim — best measured GEMM: 259-261us, 0 conflicts):
// 256x256 GEMM, 16x16x32 MFMA, 8 waves x 128x64 wave-tile. Register-pipelined
// phases; ONE boundary per tile: barrier -> stage t+2 (8 gloads) -> counted
// WAIT_VM(8) -> barrier -> prefetch next ph0 fragments. Never vmcnt(0) until
// the final drain. B frags double-banked (bFe/bFo).
// ---------------------------------------------------------------------------
__device__ __forceinline__ void gld(const bf16_t* src, char* dst) {
  __builtin_amdgcn_global_load_lds((const __attribute__((address_space(1))) void*)src,
                                   (__attribute__((address_space(3))) void*)dst, 16, 0, 0);
}

#define BARRIER() __builtin_amdgcn_s_barrier()
#define SBAR()    __builtin_amdgcn_sched_barrier(0)
#define WAIT_VM(n) asm volatile("s_waitcnt vmcnt(" #n ")" ::: "memory")

#define LDA(buf, m, cb) (*(const bf16x8*)(ldsA + ((buf)*32768 + aRowB + (m)*2048 + (cb))))
#define LDB(buf, n, cb) (*(const bf16x8*)(ldsB + ((buf)*32768 + bRowB + (n)*2048 + (cb))))

#define STAGE_A4(kt, buf) do { \
  _Pragma("unroll") for (int g = 0; g < 4; ++g) \
    gld(Asrc + ((size_t)g*64*IN_F + (size_t)(kt)*64), ldsA + ((buf)*32768 + g*8192 + tid*16)); \
} while (0)
#define STAGE_B4(kt, buf) do { \
  _Pragma("unroll") for (int g = 0; g < 4; ++g) \
    gld(Bsrc + ((size_t)g*64*IN_F + (size_t)(kt)*64), ldsB + ((buf)*32768 + g*8192 + tid*16)); \
} while (0)

#define LOADA2(dst, m0, buf) do { \
  dst[0][0] = LDA(buf, m0,     cA0); dst[0][1] = LDA(buf, m0,     cA1); \
  dst[1][0] = LDA(buf, (m0)+1, cA0); dst[1][1] = LDA(buf, (m0)+1, cA1); \
} while (0)

#define PREFETCH12(buf, BFN) do { \
  LOADA2(aF0, 0, buf); \
  _Pragma("unroll") for (int n = 0; n < 4; ++n) { \
    BFN[n][0] = LDB(buf, n, cA0); BFN[n][1] = LDB(buf, n, cA1); } \
} while (0)

#define MFMA_Q(Q, AF, BF) do { \
  SBAR(); \
  __builtin_amdgcn_s_setprio(1); \
  _Pragma("unroll") for (int kh = 0; kh < 2; ++kh) \
  _Pragma("unroll") for (int mm = 0; mm < 2; ++mm) \
  _Pragma("unroll") for (int n = 0; n < 4; ++n) \
    acc[2*(Q)+mm][n] = __builtin_amdgcn_mfma_f32_16x16x32_bf16( \
        AF[mm][kh], BF[n][kh], acc[2*(Q)+mm][n], 0, 0, 0); \
  __builtin_amdgcn_s_setprio(0); \
} while (0)

#define TILE_BODY(CUR, BFC) do { \
  LOADA2(aF1, 2, CUR); MFMA_Q(0, aF0, BFC); \
  LOADA2(aF0, 4, CUR); MFMA_Q(1, aF1, BFC); \
  LOADA2(aF1, 6, CUR); MFMA_Q(2, aF0, BFC); \
  MFMA_Q(3, aF1, BFC); \
} while (0)

#define TILE_END(CUR, tv, BFN) do { \
  SBAR(); BARRIER(); \
  if ((tv) < 62) { STAGE_A4((tv) + 2, CUR); STAGE_B4((tv) + 2, CUR); \
                   SBAR(); WAIT_VM(8); } \
  else           { WAIT_VM(0); } \
  SBAR(); BARRIER(); SBAR(); \
  PREFETCH12((CUR) ^ 1, BFN); \
} while (0)

__global__ __launch_bounds__(512, 2)
void gemm_pipe_kernel(const bf16_t* __restrict__ Xb, const bf16_t* __restrict__ Wp,
                      const float* __restrict__ bias, float* __restrict__ C) {
  __shared__ __align__(16) bf16_t As[2 * 16384];   // 64 KiB [2buf][256][64]
  __shared__ __align__(16) bf16_t Bs[2 * 16384];   // 64 KiB
  char* ldsA = (char*)As;
  char* ldsB = (char*)Bs;

  const int tid  = threadIdx.x;
  const int lane = tid & 63;
  const int wave = tid >> 6;
  const int wr = wave >> 2;           // 0..1 -> M half
  const int wc = wave & 3;            // 0..3 -> N quarter
  const int r16 = lane & 15;
  const int kg  = lane >> 4;          // 0..3

  const int bid = blockIdx.x;
  const int bm = bid >> 4;            // 0..31
  const int bn = bid & 15;            // 0..15

  // staging: per-thread row + pre-swizzled source column (both-sides pair)
  const int sr = tid >> 3;                          // 0..63
  const int sc = ((tid & 7) ^ (sr & 7)) << 3;       // element col (swizzled)
  const bf16_t* Asrc = Xb + (size_t)(bm * 256 + sr) * IN_F + sc;
  const bf16_t* Bsrc = Wp + (size_t)(bn * 256 + sr) * IN_F + sc;

  // read-side offsets (proven conflict-free addressing family)
  const int aRowB = (wr * 128 + r16) * 128;         // byte row offset in A tile
  const int bRowB = (wc * 64 + r16) * 128;          // byte row offset in B tile
  const int cA0 = (kg * 16) ^ ((r16 & 7) << 4);     // swizzled col byte, k-half 0
  const int cA1 = cA0 ^ 64;                         // k-half 1

  f32x4 acc[8][4] = {};
  bf16x8 aF0[2][2], aF1[2][2], bFe[4][2], bFo[4][2];

  // prologue: stage tiles 0 and 1; prefetch tile-0 ph0 fragments
  STAGE_A4(0, 0); STAGE_B4(0, 0);
  STAGE_A4(1, 1); STAGE_B4(1, 1);
  WAIT_VM(8);                 // tile 0 landed (tile 1's 8 still in flight)
  BARRIER(); SBAR();
  PREFETCH12(0, bFe);

  for (int tt = 0; tt < 62; tt += 2) {
    TILE_BODY(0, bFe); TILE_END(0, tt,     bFo);
    TILE_BODY(1, bFo); TILE_END(1, tt + 1, bFe);
  }
  TILE_BODY(0, bFe); TILE_END(0, 62, bFo);   // t=62 (drains to 0, prefetches t63)
  TILE_BODY(1, bFo);                         // t=63

  // epilogue: C/D layout col=lane&15, row=kg*4+reg (m89-verified)
#pragma unroll
  for (int n = 0; n < 4; ++n) {
    const int col = bn * 256 + wc * 64 + n * 16 + r16;
    const float bv = bias[col];
#pragma unroll
    for (int m = 0; m < 8; ++m) {
      const int row0 = bm * 256 + wr * 128 + m * 16 + kg * 4;
#pragma unroll
      for (int r = 0; r < 4; ++r)
        C[(size_t)(row0 + r) * OUT_F + col] = acc[m][n][r] + bv;
    }
  }
}

// ---------------------------------------------------------------------------
extern "C" void kernel_launch(void* const* d_in, const int* in_sizes, int n_in,
                              void* d_out, int out_size, void* d_ws, size_t ws_size,
                              hipStream_t stream) {
  const float* x  = (const float*)d_in[0];
  const int*   qw = (const int*)d_in[1];
  const float* wm = (const float*)d_in[2];
  const float* lA = (const float*)d_in[3];
  const float* lB = (const float*)d_in[4];
  const float* bs = (const float*)d_in[5];
  float* out = (float*)d_out;

  bf16_t* Wp = (bf16_t*)d_ws;                                        // 33.5 MB
  bf16_t* Xb = (bf16_t*)((char*)d_ws + (size_t)OUT_F * IN_F * 2);    // 67 MB

  dequant_lora_kernel<<<8192, 256, 0, stream>>>(qw, wm, lA, lB, Wp);
  f32_to_bf16_kernel<<<M_ROWS * IN_F / 8 / 256, 256, 0, stream>>>(x, Xb);
  gemm_pipe_kernel<<<(M_ROWS / 256) * (OUT_F / 256), 512, 0, stream>>>(Xb, Wp, bs, out);
}